// Round 6
// baseline (237.184 us; speedup 1.0000x reference)
//
#include <hip/hip_runtime.h>

#define AS1 __attribute__((address_space(1)))
#define AS3 __attribute__((address_space(3)))

typedef __attribute__((ext_vector_type(8))) short short8;
typedef __attribute__((ext_vector_type(4))) float floatx4;

// ---- bf16 helpers (RNE; inputs are finite, no NaN/Inf handling needed) ----
__device__ __forceinline__ short f2bf(float f) {
  union { float f; unsigned u; } v; v.f = f;
  return (short)((v.u + 0x7fffu + ((v.u >> 16) & 1u)) >> 16);
}
__device__ __forceinline__ float bf2f(short s) {
  union { unsigned u; float f; } v; v.u = ((unsigned)(unsigned short)s) << 16;
  return v.f;
}

// ---- async global->LDS, 16B per lane (wave-uniform LDS base + lane*16) ----
__device__ __forceinline__ void gload_lds16(const void* g, void* l) {
  __builtin_amdgcn_global_load_lds((const AS1 unsigned*)g, (AS3 unsigned*)l, 16, 0, 0);
}

// Stage a 128x64 bf16 tile (rows rowBase..+127, cols kBase..+63) of row-major G
// (leading dim `ld` elements) into 128x64 LDS with XOR-SWIZZLED chunk layout
// (r6): source 16B-chunk index is (lane&7) ^ (row&7) — row&7 = (lane>>3)&7 for
// every c-group, so one per-thread offset covers all 16 row-groups. LDS dest
// stays linear (rule #21: swizzle source + read, never the gload dest).
// Coalescing unchanged: permutation stays inside each 8-lane 128B segment.
__device__ __forceinline__ void stage128x64(const short* __restrict__ G, long rowBase, long ld,
                                            int kBase, short* lds, int lane, int wave) {
  const int chunk = (lane & 7) ^ ((lane >> 3) & 7);
  const short* gb = G + rowBase * ld + (long)kBase + (long)(lane >> 3) * ld + chunk * 8;
#pragma unroll
  for (int j = 0; j < 4; ++j) {
    int c = wave * 4 + j;
    gload_lds16(gb + (long)c * 8 * ld, lds + c * 512);
  }
}

// One BK=64 step of 128x128 MFMA tile compute. Wave (wm,wn) owns a 64x64 C block.
// r6: ds_read col is XOR-swizzled to match stage128x64 (row&7 == lane&7 for all
// fragment rows). Kills the 16-way bank conflict (128B row stride, 16 lanes
// same column) -> 2-way aliasing (free, m136). Bit-identical output.
__device__ __forceinline__ void mfma_step(const short* lA, const short* lB, floatx4 acc[4][4],
                                          int lane, int wm, int wn) {
#pragma unroll
  for (int kk = 0; kk < 64; kk += 32) {
    short8 a[4], b[4];
    int kq = (kk + (lane >> 4) * 8) ^ ((lane & 7) << 3);
#pragma unroll
    for (int i = 0; i < 4; ++i) {
      a[i] = *(const short8*)(lA + (wm * 64 + i * 16 + (lane & 15)) * 64 + kq);
      b[i] = *(const short8*)(lB + (wn * 64 + i * 16 + (lane & 15)) * 64 + kq);
    }
#pragma unroll
    for (int i = 0; i < 4; ++i)
#pragma unroll
      for (int j = 0; j < 4; ++j)
        acc[i][j] = __builtin_amdgcn_mfma_f32_16x16x32_bf16(a[i], b[j], acc[i][j], 0, 0, 0);
  }
}

// Causal (qt,kt) pair LUT, supertile-major order. Entry = (qt<<4)|kt.
__device__ const unsigned char PAIR_LUT[136] = {
  // s(1,0) 16
  0x40,0x41,0x42,0x43,0x50,0x51,0x52,0x53,0x60,0x61,0x62,0x63,0x70,0x71,0x72,0x73,
  // s(2,0) 16
  0x80,0x81,0x82,0x83,0x90,0x91,0x92,0x93,0xA0,0xA1,0xA2,0xA3,0xB0,0xB1,0xB2,0xB3,
  // s(2,1) 16
  0x84,0x85,0x86,0x87,0x94,0x95,0x96,0x97,0xA4,0xA5,0xA6,0xA7,0xB4,0xB5,0xB6,0xB7,
  // s(3,0) 16
  0xC0,0xC1,0xC2,0xC3,0xD0,0xD1,0xD2,0xD3,0xE0,0xE1,0xE2,0xE3,0xF0,0xF1,0xF2,0xF3,
  // s(3,1) 16
  0xC4,0xC5,0xC6,0xC7,0xD4,0xD5,0xD6,0xD7,0xE4,0xE5,0xE6,0xE7,0xF4,0xF5,0xF6,0xF7,
  // s(3,2) 16
  0xC8,0xC9,0xCA,0xCB,0xD8,0xD9,0xDA,0xDB,0xE8,0xE9,0xEA,0xEB,0xF8,0xF9,0xFA,0xFB,
  // D(0,0) 10
  0x00,0x10,0x11,0x20,0x21,0x22,0x30,0x31,0x32,0x33,
  // D(1,1) 10
  0x44,0x54,0x55,0x64,0x65,0x66,0x74,0x75,0x76,0x77,
  // D(2,2) 10
  0x88,0x98,0x99,0xA8,0xA9,0xAA,0xB8,0xB9,0xBA,0xBB,
  // D(3,3) 10
  0xCC,0xDC,0xDD,0xEC,0xED,0xEE,0xFC,0xFD,0xFE,0xFF
};

// ---- stage 0 (fused): [0,8192) convert X; [8192,11264) transpose W; [11264,11296) zero l ----
__global__ void prep_inputs(const float* __restrict__ X, const float* __restrict__ Wq,
                            const float* __restrict__ Wk, const float* __restrict__ Wv,
                            short* __restrict__ Xb, short* __restrict__ Wt,
                            float* __restrict__ l) {
  __shared__ float t[32][33];
  if (blockIdx.x < 8192) {
    long i = ((long)blockIdx.x * 256 + threadIdx.x) * 4;
    float4 v = *(const float4*)(X + i);
    short4 o;
    o.x = f2bf(v.x); o.y = f2bf(v.y); o.z = f2bf(v.z); o.w = f2bf(v.w);
    *(short4*)(Xb + i) = o;
  } else if (blockIdx.x < 11264) {
    int idx = blockIdx.x - 8192;           // [0,3072): z*1024 + bx*32 + by
    int z = idx >> 10, rem = idx & 1023;
    int bx = rem >> 5, by = rem & 31;
    const float* W = z == 0 ? Wq : (z == 1 ? Wk : Wv);
    short* O = Wt + (long)z * 1024 * 1024;
    int tx = threadIdx.x & 31, ty = threadIdx.x >> 5;
    int x = bx * 32 + tx;
    int y0 = by * 32;
    for (int j = ty; j < 32; j += 8)
      t[j][tx] = W[(long)(y0 + j) * 1024 + x];
    __syncthreads();
    int x2 = by * 32 + tx;
    int y2 = bx * 32;
    for (int j = ty; j < 32; j += 8)
      O[(long)(y2 + j) * 1024 + x2] = f2bf(t[tx][j]);
  } else {
    l[(blockIdx.x - 11264) * 256 + threadIdx.x] = 0.0f;
  }
}

// ============================================================================
// stage 1: Q/K/V = X @ W — 256x256 tile, BK=64, 8 waves, 4-phase/K-tile with
// ONE-PHASE-AHEAD register pipelining (r5, frozen — best measured 65.7us):
//   Every lgkm wait drains only reads issued >=1 phase earlier, so each
//   phase's just-issued ds_reads drain UNDER the current MFMA cluster.
// See r5 ledger comments below; verified bit-identical.
// ============================================================================
#define LOFF(b, m, h) ((((b) * 2 + (m)) * 2 + (h)) * 8192)
#define MEMFENCE() asm volatile("" ::: "memory")
#define SBAR() do { MEMFENCE(); __builtin_amdgcn_s_barrier(); MEMFENCE(); } while (0)
#define SCHEDB() __builtin_amdgcn_sched_barrier(0)

// Stage one 128x64 half-tile with 512 threads (2 x global_load_lds each).
// Global source column is pre-swizzled: chunk = (tid&7) ^ ((tid>>3)&7), so the
// linear LDS write lands data in XOR-swizzled position (rule #21).
__device__ __forceinline__ void stage_half(const short* __restrict__ g, short* l, int wv) {
  gload_lds16(g, l + wv * 512);                    // rows 0..63   (chunk j=0)
  gload_lds16(g + 65536, l + 4096 + wv * 512);     // rows 64..127 (chunk j=1)
}

// Swizzled ds_read_b128 of one MFMA fragment: within-half row = row+(lane&15),
// col = kq ^ ((r&7)<<3) (r&7 == lane&7 since row is a multiple of 16).
__device__ __forceinline__ short8 lds_rd(const short* l, int row, int kk, int lane) {
  const int r = row + (lane & 15);
  const int c = (kk + ((lane >> 4) << 3)) ^ ((lane & 7) << 3);
  return *(const short8*)(l + r * 64 + c);
}

__global__ __launch_bounds__(512, 2) void gemm_qkv(const short* __restrict__ Xb,
                                                   const short* __restrict__ Wt,
                                                   short* __restrict__ Q, short* __restrict__ K2,
                                                   short* __restrict__ Vt) {
  // [buf][mat A=0/B=1][half][128*64] = 128 KiB
  __shared__ __align__(16) short lds[65536];
  const int tid = threadIdx.x;
  const int lane = tid & 63, wv = tid >> 6;
  const int wm = wv >> 2, wn = wv & 3;   // 2 x 4 wave grid; per-wave C = 128x64

  // T1: XCD-chunked mapping (384 = 8 XCDs * 48). ng varies FASTEST within an
  // XCD so concurrent blocks share the A panel (4 distinct mt per XCD, 2MB,
  // L2-resident) and stream B K-slices.
  const int bid = blockIdx.x;
  const int xcd = bid & 7, w = bid >> 3;           // w in [0,48)
  const int mt = xcd * 4 + (w / 12);               // [0,32)
  const int ng = w % 12;                           // z*4 + n_tile
  const int z = ng >> 2;
  const long mBase = (long)mt * 256;
  const long nBase = (long)(ng & 3) * 256;
  const short* Bm = Wt + (long)z * 1048576;

  // per-thread staging source (pre-swizzled column chunk)
  const int r0 = tid >> 3;                          // 0..63
  const int cc = ((tid & 7) ^ (r0 & 7)) << 3;       // element offset, 16B chunk
  const short* gA = Xb + (mBase + r0) * 1024 + cc;
  const short* gB = Bm + (nBase + r0) * 1024 + cc;

  floatx4 acc[8][4];
  const floatx4 zero = {0.f, 0.f, 0.f, 0.f};
#pragma unroll
  for (int i = 0; i < 8; ++i)
#pragma unroll
    for (int j = 0; j < 4; ++j) acc[i][j] = zero;

  short8 a0[4][2], a1[4][2], bq[2][2];   // live across tiles (software pipeline)

  // ---- prologue: A(0),B(0) -> buf0; A(1),B(1).h0 -> buf1; drain A(0),B(0);
  //      then issue a0(t=0) reads so tile 0 enters in steady state ----
  stage_half(gA, lds + LOFF(0, 0, 0), wv);
  stage_half(gA + 131072, lds + LOFF(0, 0, 1), wv);
  stage_half(gB, lds + LOFF(0, 1, 0), wv);
  stage_half(gB + 131072, lds + LOFF(0, 1, 1), wv);
  stage_half(gA + 64, lds + LOFF(1, 0, 0), wv);
  stage_half(gA + 64 + 131072, lds + LOFF(1, 0, 1), wv);
  stage_half(gB + 64, lds + LOFF(1, 1, 0), wv);
  asm volatile("s_waitcnt vmcnt(6)" ::: "memory");  // A(0),B(0) resident; 3 half-tiles in flight
  SBAR();
  {
    const short* Ab0 = lds + LOFF(0, 0, wm);
#pragma unroll
    for (int f = 0; f < 4; ++f) a0[f][0] = lds_rd(Ab0, f * 16, 0, lane);
#pragma unroll
    for (int f = 0; f < 4; ++f) a0[f][1] = lds_rd(Ab0, f * 16, 32, lane);
  }

#pragma unroll 2
  for (int t = 0; t < 16; ++t) {
    const int buf = t & 1;
    const short* Ab  = lds + LOFF(buf, 0, wm);        // this wave's A half
    const short* Bb  = lds + LOFF(buf, 1, (wn >> 1)); // this wave's B half
    const short* AbN = lds + LOFF(buf ^ 1, 0, wm);    // next tile's A half
    const int brow = (wn & 1) * 64;

    // ---- ph1: rd b0->bq + a1; stage B(t+1).h1; lgkm(8); MFMA a0 x b0 ----
    bq[0][0] = lds_rd(Bb, brow, 0, lane);
    bq[1][0] = lds_rd(Bb, brow + 16, 0, lane);
    bq[0][1] = lds_rd(Bb, brow, 32, lane);
    bq[1][1] = lds_rd(Bb, brow + 16, 32, lane);
#pragma unroll
    for (int f = 0; f < 4; ++f) a1[f][0] = lds_rd(Ab, 64 + f * 16, 0, lane);
#pragma unroll
    for (int f = 0; f < 4; ++f) a1[f][1] = lds_rd(Ab, 64 + f * 16, 32, lane);
    if (t < 15) stage_half(gB + (t + 1) * 64 + 131072, lds + LOFF(buf ^ 1, 1, 1), wv);
    asm volatile("s_waitcnt lgkmcnt(8)" ::: "memory");  // a0,b0 ready; a1 in flight
    SCHEDB();
    __builtin_amdgcn_s_setprio(1);
#pragma unroll
    for (int f = 0; f < 4; ++f)
#pragma unroll
      for (int n = 0; n < 2; ++n)
        acc[f][n] = __builtin_amdgcn_mfma_f32_16x16x32_bf16(a0[f][0], bq[n][0], acc[f][n], 0, 0, 0);
#pragma unroll
    for (int f = 0; f < 4; ++f)
#pragma unroll
      for (int n = 0; n < 2; ++n)
        acc[f][n] = __builtin_amdgcn_mfma_f32_16x16x32_bf16(a0[f][1], bq[n][1], acc[f][n], 0, 0, 0);
    __builtin_amdgcn_s_setprio(0);

    // ---- ph2: a1 drained under ph1 MFMA; MFMA a1 x b0; BAR ----
    asm volatile("s_waitcnt lgkmcnt(0)" ::: "memory");
    SCHEDB();
    __builtin_amdgcn_s_setprio(1);
#pragma unroll
    for (int f = 0; f < 4; ++f)
#pragma unroll
      for (int n = 0; n < 2; ++n)
        acc[4 + f][n] = __builtin_amdgcn_mfma_f32_16x16x32_bf16(a1[f][0], bq[n][0], acc[4 + f][n], 0, 0, 0);
#pragma unroll
    for (int f = 0; f < 4; ++f)
#pragma unroll
      for (int n = 0; n < 2; ++n)
        acc[4 + f][n] = __builtin_amdgcn_mfma_f32_16x16x32_bf16(a1[f][1], bq[n][1], acc[4 + f][n], 0, 0, 0);
    __builtin_amdgcn_s_setprio(0);
    SBAR();   // all A(t)/b0 reads done chip-wide -> A-region staging safe

    // ---- ph3: rd b1->bq (bq dead); stage A(t+2).h0; lgkm(0); MFMA a0 x b1;
    //           vmcnt checkpoint; BAR ----
    bq[0][0] = lds_rd(Bb, brow + 32, 0, lane);
    bq[1][0] = lds_rd(Bb, brow + 48, 0, lane);
    bq[0][1] = lds_rd(Bb, brow + 32, 32, lane);
    bq[1][1] = lds_rd(Bb, brow + 48, 32, lane);
    if (t < 14) stage_half(gA + (t + 2) * 64, lds + LOFF(buf, 0, 0), wv);
    asm volatile("s_waitcnt lgkmcnt(0)" ::: "memory");
    SCHEDB();
    __builtin_amdgcn_s_setprio(1);
#pragma unroll
    for (int f = 0; f < 4; ++f)
#pragma unroll
      for (int n = 0; n < 2; ++n)
        acc[f][2 + n] = __builtin_amdgcn_mfma_f32_16x16x32_bf16(a0[f][0], bq[n][0], acc[f][2 + n], 0, 0, 0);
#pragma unroll
    for (int f = 0; f < 4; ++f)
#pragma unroll
      for (int n = 0; n < 2; ++n)
        acc[f][2 + n] = __builtin_amdgcn_mfma_f32_16x16x32_bf16(a0[f][1], bq[n][1], acc[f][2 + n], 0, 0, 0);
    __builtin_amdgcn_s_setprio(0);
    if (t < 14) { asm volatile("s_waitcnt vmcnt(2)" ::: "memory"); }
    else        { asm volatile("s_waitcnt vmcnt(0)" ::: "memory"); }
    SBAR();   // A(t+1),B(t+1) resident chip-wide; b-reads of tile t done

    // ---- ph4: rd a0'(next tile, a0 dead); stage A(t+2).h1 + B(t+2).h0;
    //           MFMA a1 x b1 (no wait; a0' drains under it) ----
    if (t < 15) {
#pragma unroll
      for (int f = 0; f < 4; ++f) a0[f][0] = lds_rd(AbN, f * 16, 0, lane);
#pragma unroll
      for (int f = 0; f < 4; ++f) a0[f][1] = lds_rd(AbN, f * 16, 32, lane);
    }
    if (t < 14) {
      stage_half(gA + (t + 2) * 64 + 131072, lds + LOFF(buf, 0, 1), wv);
      stage_half(gB + (t + 2) * 64, lds + LOFF(buf, 1, 0), wv);
    }
    SCHEDB();   // pin a0' issue + staging BEFORE the MFMA cluster
    __builtin_amdgcn_s_setprio(1);
#pragma unroll
    for (int f = 0; f < 4; ++f)
#pragma unroll
      for (int n = 0; n < 2; ++n)
        acc[4 + f][2 + n] = __builtin_amdgcn_mfma_f32_16x16x32_bf16(a1[f][0], bq[n][0], acc[4 + f][2 + n], 0, 0, 0);
#pragma unroll
    for (int f = 0; f < 4; ++f)
#pragma unroll
      for (int n = 0; n < 2; ++n)
        acc[4 + f][2 + n] = __builtin_amdgcn_mfma_f32_16x16x32_bf16(a1[f][1], bq[n][1], acc[4 + f][2 + n], 0, 0, 0);
    __builtin_amdgcn_s_setprio(0);
  }

  // ---- epilogue ----
  if (z < 2) {
    short* outp = (z == 0) ? Q : K2;
#pragma unroll
    for (int f = 0; f < 8; ++f)
#pragma unroll
      for (int n = 0; n < 4; ++n) {
        const int col = (int)nBase + wn * 64 + n * 16 + (lane & 15);
#pragma unroll
        for (int rr = 0; rr < 4; ++rr) {
          const long m = mBase + wm * 128 + f * 16 + ((lane >> 4) << 2) + rr;
          outp[m * 1024 + col] = f2bf(acc[f][n][rr]);
        }
      }
  } else {
    // V transposed write: in Vt[b][d][s], the 4 r-values are s-contiguous
    const long bz = mBase >> 11;
    const int sB = (int)(mBase & 2047);
#pragma unroll
    for (int f = 0; f < 8; ++f) {
      const int s0 = sB + wm * 128 + f * 16 + ((lane >> 4) << 2);
#pragma unroll
      for (int n = 0; n < 4; ++n) {
        const int col = (int)nBase + wn * 64 + n * 16 + (lane & 15);
        short4 o;
        o.x = f2bf(acc[f][n][0]); o.y = f2bf(acc[f][n][1]);
        o.z = f2bf(acc[f][n][2]); o.w = f2bf(acc[f][n][3]);
        *(short4*)(Vt + ((bz * 1024 + col) * 2048 + s0)) = o;
      }
    }
  }
}

// ---- stage 2: E = exp(Q K^T / 32) on causal block pairs; row sums into l ----
__global__ __launch_bounds__(256, 4) void scores_exp(const short* __restrict__ Q,
                                                     const short* __restrict__ Kk,
                                                     short* __restrict__ E, float* __restrict__ l) {
  __shared__ short lbuf[16384];  // lA=lbuf[0:8192), lB=lbuf[8192:16384); epilogue: 128x128 E tile
  short* lA = lbuf;
  short* lB = lbuf + 8192;
  const int lane = threadIdx.x & 63, wave = threadIdx.x >> 6;
  const int wm = wave >> 1, wn = wave & 1;
  const int b = blockIdx.y;

  const int r = blockIdx.x & 7, w = blockIdx.x >> 3;  // grid.x = 136 = 8*17
  const int code = PAIR_LUT[r * 17 + w];
  const int qt = code >> 4, kt = code & 15;

  const long rowQ = (long)b * 2048 + (long)qt * 128;
  const long rowK = (long)b * 2048 + (long)kt * 128;

  floatx4 acc[4][4];
  const floatx4 zero = {0.f, 0.f, 0.f, 0.f};
#pragma unroll
  for (int i = 0; i < 4; ++i)
#pragma unroll
    for (int j = 0; j < 4; ++j) acc[i][j] = zero;

  for (int it = 0; it < 16; ++it) {
    stage128x64(Q, rowQ, 1024, it * 64, lA, lane, wave);
    stage128x64(Kk, rowK, 1024, it * 64, lB, lane, wave);
    __syncthreads();
    mfma_step(lA, lB, acc, lane, wm, wn);
    __syncthreads();
  }
  // last loop iter ended with __syncthreads(): lbuf is free for the epilogue tile.

  float* lrow = l + (long)b * 2048;
#pragma unroll
  for (int i = 0; i < 4; ++i) {
#pragma unroll
    for (int rr = 0; rr < 4; ++rr) {
      int ri = wm * 64 + i * 16 + (lane >> 4) * 4 + rr;
      int qrow = qt * 128 + ri;
      float psum = 0.f;
#pragma unroll
      for (int j = 0; j < 4; ++j) {
        int ci = wn * 64 + j * 16 + (lane & 15);
        int col = kt * 128 + ci;
        float sc = acc[i][j][rr] * 0.03125f;  // 1/sqrt(1024)
        float e = (col <= qrow) ? __expf(sc) : 0.0f;
        short eb = f2bf(e);
        lbuf[ri * 128 + ((((ci >> 3) ^ (ri & 15)) << 3) | (ci & 7))] = eb;
        psum += bf2f(eb);
      }
      for (int m = 1; m < 16; m <<= 1) psum += __shfl_xor(psum, m, 64);
      if ((lane & 15) == 0) atomicAdd(&lrow[qrow], psum);
    }
  }
  __syncthreads();

  short* Eb = E + (long)b * 4194304;
  const long ebase = (long)(qt * 128) * 2048 + kt * 128;
#pragma unroll
  for (int pp = 0; pp < 8; ++pp) {
    int g = pp * 256 + threadIdx.x;
    int row = g >> 4, c = g & 15;
    short8 v = *(const short8*)(lbuf + row * 128 + ((c ^ (row & 15)) << 3));
    *(short8*)(Eb + ebase + (long)row * 2048 + c * 8) = v;
  }
}

// ---- stage 3: O = (E @ V) / l, split-K + XCD-locality swizzle ----
__global__ __launch_bounds__(256, 4) void pv_gemm(const short* __restrict__ E,
                                                  const short* __restrict__ Vt,
                                                  const float* __restrict__ l,
                                                  float* __restrict__ part,
                                                  float* __restrict__ out) {
  __shared__ short lA[128 * 64], lB[128 * 64];
  const int lane = threadIdx.x & 63, wave = threadIdx.x >> 6;
  const int wm = wave >> 1, wn = wave & 1;
  const int xx = blockIdx.x;            // [0,192)
  const int dt = xx / 24;
  const int within = xx % 24;
  const int r = within & 7, wsel = within >> 3;  // wsel in {0,1,2}
  const int b = blockIdx.y;

  int qt, it0, it1, mode;  // mode: 0 direct(/l), 1 chunk0->out raw, 2 chunk1->part raw
  if (wsel == 2) {
    qt = r; it0 = 0; it1 = (qt + 1) * 2; mode = 0;
  } else {
    qt = 15 - r;
    const int T = (qt + 1) * 2, c0 = T >> 1;
    if (wsel == 0) { it0 = 0;  it1 = c0; mode = 1; }
    else           { it0 = c0; it1 = T;  mode = 2; }
  }

  const short* Eb = E + (long)b * 2048 * 2048;
  const short* Vb = Vt + (long)b * 1024 * 2048;
  const float* lrow = l + (long)b * 2048;

  floatx4 acc[4][4];
  const floatx4 zero = {0.f, 0.f, 0.f, 0.f};
#pragma unroll
  for (int i = 0; i < 4; ++i)
#pragma unroll
    for (int j = 0; j < 4; ++j) acc[i][j] = zero;

  for (int it = it0; it < it1; ++it) {
    stage128x64(Eb, (long)qt * 128, 2048, it * 64, lA, lane, wave);
    stage128x64(Vb, (long)dt * 128, 2048, it * 64, lB, lane, wave);
    __syncthreads();
    mfma_step(lA, lB, acc, lane, wm, wn);
    __syncthreads();
  }

  if (mode == 2) {
    float* P = part + ((((long)b * 8 + (qt - 8)) * 8 + dt) << 14);
#pragma unroll
    for (int i = 0; i < 4; ++i)
#pragma unroll
      for (int rr = 0; rr < 4; ++rr) {
        int ri = wm * 64 + i * 16 + (lane >> 4) * 4 + rr;
#pragma unroll
        for (int j = 0; j < 4; ++j) {
          int ci = wn * 64 + j * 16 + (lane & 15);
          P[ri * 128 + ci] = acc[i][j][rr];
        }
      }
  } else {
#pragma unroll
    for (int i = 0; i < 4; ++i)
#pragma unroll
      for (int rr = 0; rr < 4; ++rr) {
        int qrow = qt * 128 + wm * 64 + i * 16 + (lane >> 4) * 4 + rr;
        float scale = (mode == 0) ? 1.0f / lrow[qrow] : 1.0f;
#pragma unroll
        for (int j = 0; j < 4; ++j) {
          int d = dt * 128 + wn * 64 + j * 16 + (lane & 15);
          out[((long)b * 2048 + qrow) * 1024 + d] = acc[i][j][rr] * scale;
        }
      }
  }
}

// ---- stage 4: rows qt>=8: out = (out + part)/l ----
__global__ void pv_reduce(float* __restrict__ out, const float* __restrict__ part,
                          const float* __restrict__ l) {
  const int idx = blockIdx.x;           // 4096 = 4b * 1024 rows
  const int b = idx >> 10;
  const int row = 1024 + (idx & 1023);  // global row in [1024, 2048)
  const int t = threadIdx.x;
  const int dt = t >> 5, dl = (t << 2) & 127;
  const float inv = 1.0f / l[((long)b << 11) + row];
  const long pbase = ((((long)b * 8 + ((row >> 7) - 8)) * 8 + dt) << 14) + ((row & 127) << 7) + dl;
  const long obase = (((long)b * 2048 + row) << 10) + (t << 2);
  float4 o = *(const float4*)(out + obase);
  float4 p = *(const float4*)(part + pbase);
  o.x = (o.x + p.x) * inv; o.y = (o.y + p.y) * inv;
  o.z = (o.z + p.z) * inv; o.w = (o.w + p.w) * inv;
  *(float4*)(out + obase) = o;
}

extern "C" void kernel_launch(void* const* d_in, const int* in_sizes, int n_in,
                              void* d_out, int out_size, void* d_ws, size_t ws_size,
                              hipStream_t stream) {
  const float* X  = (const float*)d_in[0];
  const float* Wq = (const float*)d_in[1];
  const float* Wk = (const float*)d_in[2];
  const float* Wv = (const float*)d_in[3];

  char* ws = (char*)d_ws;
  // layout (bytes): Xb 16M (reused as pv partials) | Wt 6M | Q 16M | K 16M | Vt 16M | E 32M | l 32K
  short* Xb = (short*)(ws);
  short* Wt = (short*)(ws + 16777216L);
  short* Q  = (short*)(ws + 23068672L);
  short* K2 = (short*)(ws + 39845888L);
  short* Vt = (short*)(ws + 56623104L);
  short* E  = (short*)(ws + 73400320L);
  float* l  = (float*)(ws + 106954752L);
  float* part = (float*)(ws);  // 256 tiles * 64KB = 16MB, overlays dead Xb

  prep_inputs<<<11296, 256, 0, stream>>>(X, Wq, Wk, Wv, Xb, Wt, l);
  gemm_qkv<<<384, 512, 0, stream>>>(Xb, Wt, Q, K2, Vt);
  scores_exp<<<dim3(136, 4), 256, 0, stream>>>(Q, K2, E, l);
  pv_gemm<<<dim3(192, 4), 256, 0, stream>>>(E, Vt, l, part, (float*)d_out);
  pv_reduce<<<4096, 256, 0, stream>>>((float*)d_out, part, l);
}

// Round 7
// 236.567 us; speedup vs baseline: 1.0026x; 1.0026x over previous
//
#include <hip/hip_runtime.h>

#define AS1 __attribute__((address_space(1)))
#define AS3 __attribute__((address_space(3)))

typedef __attribute__((ext_vector_type(8))) short short8;
typedef __attribute__((ext_vector_type(4))) float floatx4;

// ---- bf16 helpers (RNE; inputs are finite, no NaN/Inf handling needed) ----
__device__ __forceinline__ short f2bf(float f) {
  union { float f; unsigned u; } v; v.f = f;
  return (short)((v.u + 0x7fffu + ((v.u >> 16) & 1u)) >> 16);
}
__device__ __forceinline__ float bf2f(short s) {
  union { unsigned u; float f; } v; v.u = ((unsigned)(unsigned short)s) << 16;
  return v.f;
}

// ---- async global->LDS, 16B per lane (wave-uniform LDS base + lane*16) ----
__device__ __forceinline__ void gload_lds16(const void* g, void* l) {
  __builtin_amdgcn_global_load_lds((const AS1 unsigned*)g, (AS3 unsigned*)l, 16, 0, 0);
}

// Stage a 128x64 bf16 tile of row-major G into 128x64 LDS with XOR-swizzled
// chunk layout (source chunk = (lane&7) ^ (row&7); LDS dest linear, rule #21).
// 256 threads / 4 waves; 4 gloads per thread.
__device__ __forceinline__ void stage128x64(const short* __restrict__ G, long rowBase, long ld,
                                            int kBase, short* lds, int lane, int wave) {
  const int chunk = (lane & 7) ^ ((lane >> 3) & 7);
  const short* gb = G + rowBase * ld + (long)kBase + (long)(lane >> 3) * ld + chunk * 8;
#pragma unroll
  for (int j = 0; j < 4; ++j) {
    int c = wave * 4 + j;
    gload_lds16(gb + (long)c * 8 * ld, lds + c * 512);
  }
}

// Swizzled ds_read_b128 of one MFMA fragment (matches stage128x64 / stage_half
// source swizzle): row multiple of 16; col = kq ^ ((lane&7)<<3).
__device__ __forceinline__ short8 lds_rd(const short* l, int row, int kk, int lane) {
  const int r = row + (lane & 15);
  const int c = (kk + ((lane >> 4) << 3)) ^ ((lane & 7) << 3);
  return *(const short8*)(l + r * 64 + c);
}

#define MEMFENCE() asm volatile("" ::: "memory")
#define SBAR() do { MEMFENCE(); __builtin_amdgcn_s_barrier(); MEMFENCE(); } while (0)
#define SCHEDB() __builtin_amdgcn_sched_barrier(0)

// Causal (qt,kt) pair LUT, supertile-major order. Entry = (qt<<4)|kt.
__device__ const unsigned char PAIR_LUT[136] = {
  // s(1,0) 16
  0x40,0x41,0x42,0x43,0x50,0x51,0x52,0x53,0x60,0x61,0x62,0x63,0x70,0x71,0x72,0x73,
  // s(2,0) 16
  0x80,0x81,0x82,0x83,0x90,0x91,0x92,0x93,0xA0,0xA1,0xA2,0xA3,0xB0,0xB1,0xB2,0xB3,
  // s(2,1) 16
  0x84,0x85,0x86,0x87,0x94,0x95,0x96,0x97,0xA4,0xA5,0xA6,0xA7,0xB4,0xB5,0xB6,0xB7,
  // s(3,0) 16
  0xC0,0xC1,0xC2,0xC3,0xD0,0xD1,0xD2,0xD3,0xE0,0xE1,0xE2,0xE3,0xF0,0xF1,0xF2,0xF3,
  // s(3,1) 16
  0xC4,0xC5,0xC6,0xC7,0xD4,0xD5,0xD6,0xD7,0xE4,0xE5,0xE6,0xE7,0xF4,0xF5,0xF6,0xF7,
  // s(3,2) 16
  0xC8,0xC9,0xCA,0xCB,0xD8,0xD9,0xDA,0xDB,0xE8,0xE9,0xEA,0xEB,0xF8,0xF9,0xFA,0xFB,
  // D(0,0) 10
  0x00,0x10,0x11,0x20,0x21,0x22,0x30,0x31,0x32,0x33,
  // D(1,1) 10
  0x44,0x54,0x55,0x64,0x65,0x66,0x74,0x75,0x76,0x77,
  // D(2,2) 10
  0x88,0x98,0x99,0xA8,0xA9,0xAA,0xB8,0xB9,0xBA,0xBB,
  // D(3,3) 10
  0xCC,0xDC,0xDD,0xEC,0xED,0xEE,0xFC,0xFD,0xFE,0xFF
};

// ---- stage 0 (fused): [0,8192) convert X; [8192,11264) transpose W; [11264,11296) zero l ----
__global__ void prep_inputs(const float* __restrict__ X, const float* __restrict__ Wq,
                            const float* __restrict__ Wk, const float* __restrict__ Wv,
                            short* __restrict__ Xb, short* __restrict__ Wt,
                            float* __restrict__ l) {
  __shared__ float t[32][33];
  if (blockIdx.x < 8192) {
    long i = ((long)blockIdx.x * 256 + threadIdx.x) * 4;
    float4 v = *(const float4*)(X + i);
    short4 o;
    o.x = f2bf(v.x); o.y = f2bf(v.y); o.z = f2bf(v.z); o.w = f2bf(v.w);
    *(short4*)(Xb + i) = o;
  } else if (blockIdx.x < 11264) {
    int idx = blockIdx.x - 8192;           // [0,3072): z*1024 + bx*32 + by
    int z = idx >> 10, rem = idx & 1023;
    int bx = rem >> 5, by = rem & 31;
    const float* W = z == 0 ? Wq : (z == 1 ? Wk : Wv);
    short* O = Wt + (long)z * 1024 * 1024;
    int tx = threadIdx.x & 31, ty = threadIdx.x >> 5;
    int x = bx * 32 + tx;
    int y0 = by * 32;
    for (int j = ty; j < 32; j += 8)
      t[j][tx] = W[(long)(y0 + j) * 1024 + x];
    __syncthreads();
    int x2 = by * 32 + tx;
    int y2 = bx * 32;
    for (int j = ty; j < 32; j += 8)
      O[(long)(y2 + j) * 1024 + x2] = f2bf(t[tx][j]);
  } else {
    l[(blockIdx.x - 11264) * 256 + threadIdx.x] = 0.0f;
  }
}

// ============================================================================
// stage 1: Q/K/V = X @ W — 256x256 tile, BK=64, 8 waves, 4-phase/K-tile with
// ONE-PHASE-AHEAD register pipelining (r5, frozen — best measured 65.7us).
// ============================================================================
#define LOFF(b, m, h) ((((b) * 2 + (m)) * 2 + (h)) * 8192)

// Stage one 128x64 half-tile with 512 threads (2 x global_load_lds each).
// Source chunk pre-swizzled: chunk = (tid&7) ^ ((tid>>3)&7); LDS dest linear.
__device__ __forceinline__ void stage_half(const short* __restrict__ g, short* l, int wv) {
  gload_lds16(g, l + wv * 512);                    // rows 0..63   (chunk j=0)
  gload_lds16(g + 65536, l + 4096 + wv * 512);     // rows 64..127 (chunk j=1)
}

__global__ __launch_bounds__(512, 2) void gemm_qkv(const short* __restrict__ Xb,
                                                   const short* __restrict__ Wt,
                                                   short* __restrict__ Q, short* __restrict__ K2,
                                                   short* __restrict__ Vt) {
  // [buf][mat A=0/B=1][half][128*64] = 128 KiB
  __shared__ __align__(16) short lds[65536];
  const int tid = threadIdx.x;
  const int lane = tid & 63, wv = tid >> 6;
  const int wm = wv >> 2, wn = wv & 3;   // 2 x 4 wave grid; per-wave C = 128x64

  // T1: XCD-chunked mapping (384 = 8 XCDs * 48), ng-fastest.
  const int bid = blockIdx.x;
  const int xcd = bid & 7, w = bid >> 3;           // w in [0,48)
  const int mt = xcd * 4 + (w / 12);               // [0,32)
  const int ng = w % 12;                           // z*4 + n_tile
  const int z = ng >> 2;
  const long mBase = (long)mt * 256;
  const long nBase = (long)(ng & 3) * 256;
  const short* Bm = Wt + (long)z * 1048576;

  // per-thread staging source (pre-swizzled column chunk)
  const int r0 = tid >> 3;                          // 0..63
  const int cc = ((tid & 7) ^ (r0 & 7)) << 3;       // element offset, 16B chunk
  const short* gA = Xb + (mBase + r0) * 1024 + cc;
  const short* gB = Bm + (nBase + r0) * 1024 + cc;

  floatx4 acc[8][4];
  const floatx4 zero = {0.f, 0.f, 0.f, 0.f};
#pragma unroll
  for (int i = 0; i < 8; ++i)
#pragma unroll
    for (int j = 0; j < 4; ++j) acc[i][j] = zero;

  short8 a0[4][2], a1[4][2], bq[2][2];   // live across tiles (software pipeline)

  // ---- prologue ----
  stage_half(gA, lds + LOFF(0, 0, 0), wv);
  stage_half(gA + 131072, lds + LOFF(0, 0, 1), wv);
  stage_half(gB, lds + LOFF(0, 1, 0), wv);
  stage_half(gB + 131072, lds + LOFF(0, 1, 1), wv);
  stage_half(gA + 64, lds + LOFF(1, 0, 0), wv);
  stage_half(gA + 64 + 131072, lds + LOFF(1, 0, 1), wv);
  stage_half(gB + 64, lds + LOFF(1, 1, 0), wv);
  asm volatile("s_waitcnt vmcnt(6)" ::: "memory");  // A(0),B(0) resident; 3 half-tiles in flight
  SBAR();
  {
    const short* Ab0 = lds + LOFF(0, 0, wm);
#pragma unroll
    for (int f = 0; f < 4; ++f) a0[f][0] = lds_rd(Ab0, f * 16, 0, lane);
#pragma unroll
    for (int f = 0; f < 4; ++f) a0[f][1] = lds_rd(Ab0, f * 16, 32, lane);
  }

#pragma unroll 2
  for (int t = 0; t < 16; ++t) {
    const int buf = t & 1;
    const short* Ab  = lds + LOFF(buf, 0, wm);        // this wave's A half
    const short* Bb  = lds + LOFF(buf, 1, (wn >> 1)); // this wave's B half
    const short* AbN = lds + LOFF(buf ^ 1, 0, wm);    // next tile's A half
    const int brow = (wn & 1) * 64;

    // ---- ph1: rd b0->bq + a1; stage B(t+1).h1; lgkm(8); MFMA a0 x b0 ----
    bq[0][0] = lds_rd(Bb, brow, 0, lane);
    bq[1][0] = lds_rd(Bb, brow + 16, 0, lane);
    bq[0][1] = lds_rd(Bb, brow, 32, lane);
    bq[1][1] = lds_rd(Bb, brow + 16, 32, lane);
#pragma unroll
    for (int f = 0; f < 4; ++f) a1[f][0] = lds_rd(Ab, 64 + f * 16, 0, lane);
#pragma unroll
    for (int f = 0; f < 4; ++f) a1[f][1] = lds_rd(Ab, 64 + f * 16, 32, lane);
    if (t < 15) stage_half(gB + (t + 1) * 64 + 131072, lds + LOFF(buf ^ 1, 1, 1), wv);
    asm volatile("s_waitcnt lgkmcnt(8)" ::: "memory");  // a0,b0 ready; a1 in flight
    SCHEDB();
    __builtin_amdgcn_s_setprio(1);
#pragma unroll
    for (int f = 0; f < 4; ++f)
#pragma unroll
      for (int n = 0; n < 2; ++n)
        acc[f][n] = __builtin_amdgcn_mfma_f32_16x16x32_bf16(a0[f][0], bq[n][0], acc[f][n], 0, 0, 0);
#pragma unroll
    for (int f = 0; f < 4; ++f)
#pragma unroll
      for (int n = 0; n < 2; ++n)
        acc[f][n] = __builtin_amdgcn_mfma_f32_16x16x32_bf16(a0[f][1], bq[n][1], acc[f][n], 0, 0, 0);
    __builtin_amdgcn_s_setprio(0);

    // ---- ph2: a1 drained under ph1 MFMA; MFMA a1 x b0; BAR ----
    asm volatile("s_waitcnt lgkmcnt(0)" ::: "memory");
    SCHEDB();
    __builtin_amdgcn_s_setprio(1);
#pragma unroll
    for (int f = 0; f < 4; ++f)
#pragma unroll
      for (int n = 0; n < 2; ++n)
        acc[4 + f][n] = __builtin_amdgcn_mfma_f32_16x16x32_bf16(a1[f][0], bq[n][0], acc[4 + f][n], 0, 0, 0);
#pragma unroll
    for (int f = 0; f < 4; ++f)
#pragma unroll
      for (int n = 0; n < 2; ++n)
        acc[4 + f][n] = __builtin_amdgcn_mfma_f32_16x16x32_bf16(a1[f][1], bq[n][1], acc[4 + f][n], 0, 0, 0);
    __builtin_amdgcn_s_setprio(0);
    SBAR();   // all A(t)/b0 reads done chip-wide -> A-region staging safe

    // ---- ph3: rd b1->bq; stage A(t+2).h0; lgkm(0); MFMA a0 x b1; vmcnt; BAR ----
    bq[0][0] = lds_rd(Bb, brow + 32, 0, lane);
    bq[1][0] = lds_rd(Bb, brow + 48, 0, lane);
    bq[0][1] = lds_rd(Bb, brow + 32, 32, lane);
    bq[1][1] = lds_rd(Bb, brow + 48, 32, lane);
    if (t < 14) stage_half(gA + (t + 2) * 64, lds + LOFF(buf, 0, 0), wv);
    asm volatile("s_waitcnt lgkmcnt(0)" ::: "memory");
    SCHEDB();
    __builtin_amdgcn_s_setprio(1);
#pragma unroll
    for (int f = 0; f < 4; ++f)
#pragma unroll
      for (int n = 0; n < 2; ++n)
        acc[f][2 + n] = __builtin_amdgcn_mfma_f32_16x16x32_bf16(a0[f][0], bq[n][0], acc[f][2 + n], 0, 0, 0);
#pragma unroll
    for (int f = 0; f < 4; ++f)
#pragma unroll
      for (int n = 0; n < 2; ++n)
        acc[f][2 + n] = __builtin_amdgcn_mfma_f32_16x16x32_bf16(a0[f][1], bq[n][1], acc[f][2 + n], 0, 0, 0);
    __builtin_amdgcn_s_setprio(0);
    if (t < 14) { asm volatile("s_waitcnt vmcnt(2)" ::: "memory"); }
    else        { asm volatile("s_waitcnt vmcnt(0)" ::: "memory"); }
    SBAR();   // A(t+1),B(t+1) resident chip-wide; b-reads of tile t done

    // ---- ph4: rd a0'(next tile); stage A(t+2).h1 + B(t+2).h0; MFMA a1 x b1 ----
    if (t < 15) {
#pragma unroll
      for (int f = 0; f < 4; ++f) a0[f][0] = lds_rd(AbN, f * 16, 0, lane);
#pragma unroll
      for (int f = 0; f < 4; ++f) a0[f][1] = lds_rd(AbN, f * 16, 32, lane);
    }
    if (t < 14) {
      stage_half(gA + (t + 2) * 64 + 131072, lds + LOFF(buf, 0, 1), wv);
      stage_half(gB + (t + 2) * 64, lds + LOFF(buf, 1, 0), wv);
    }
    SCHEDB();   // pin a0' issue + staging BEFORE the MFMA cluster
    __builtin_amdgcn_s_setprio(1);
#pragma unroll
    for (int f = 0; f < 4; ++f)
#pragma unroll
      for (int n = 0; n < 2; ++n)
        acc[4 + f][2 + n] = __builtin_amdgcn_mfma_f32_16x16x32_bf16(a1[f][0], bq[n][0], acc[4 + f][2 + n], 0, 0, 0);
#pragma unroll
    for (int f = 0; f < 4; ++f)
#pragma unroll
      for (int n = 0; n < 2; ++n)
        acc[4 + f][2 + n] = __builtin_amdgcn_mfma_f32_16x16x32_bf16(a1[f][1], bq[n][1], acc[4 + f][2 + n], 0, 0, 0);
    __builtin_amdgcn_s_setprio(0);
  }

  // ---- epilogue ----
  if (z < 2) {
    short* outp = (z == 0) ? Q : K2;
#pragma unroll
    for (int f = 0; f < 8; ++f)
#pragma unroll
      for (int n = 0; n < 4; ++n) {
        const int col = (int)nBase + wn * 64 + n * 16 + (lane & 15);
#pragma unroll
        for (int rr = 0; rr < 4; ++rr) {
          const long m = mBase + wm * 128 + f * 16 + ((lane >> 4) << 2) + rr;
          outp[m * 1024 + col] = f2bf(acc[f][n][rr]);
        }
      }
  } else {
    // V transposed write: in Vt[b][d][s], the 4 r-values are s-contiguous
    const long bz = mBase >> 11;
    const int sB = (int)(mBase & 2047);
#pragma unroll
    for (int f = 0; f < 8; ++f) {
      const int s0 = sB + wm * 128 + f * 16 + ((lane >> 4) << 2);
#pragma unroll
      for (int n = 0; n < 4; ++n) {
        const int col = (int)nBase + wn * 64 + n * 16 + (lane & 15);
        short4 o;
        o.x = f2bf(acc[f][n][0]); o.y = f2bf(acc[f][n][1]);
        o.z = f2bf(acc[f][n][2]); o.w = f2bf(acc[f][n][3]);
        *(short4*)(Vt + ((bz * 1024 + col) * 2048 + s0)) = o;
      }
    }
  }
}

// ============================================================================
// stage 2 (r7): E = exp(Q K^T / 32) — depth-2 DBUF pipeline with counted
// vmcnt/lgkm. Per K-tile: issue 16 ds_reads (k0 then k1); lgkm(8) -> k0
// ready while k1 drains under the k0 MFMA cluster; after the read-complete
// barrier, stage tile t+2 into the just-freed buffer and wait vmcnt(8) —
// drains loads issued ONE TILE earlier (never the just-issued ones).
// LDS 64 KB -> 2 blocks/CU (~= current residency). MFMA order per
// accumulator unchanged (k0 cluster then k1) -> bit-identical output.
// ============================================================================
__global__ __launch_bounds__(256, 2) void scores_exp(const short* __restrict__ Q,
                                                     const short* __restrict__ Kk,
                                                     short* __restrict__ E, float* __restrict__ l) {
  __shared__ __align__(16) short lds[32768];  // [buf][{A,B}][8192]; epilogue reuses [0,16384)
  const int lane = threadIdx.x & 63, wave = threadIdx.x >> 6;
  const int wm = wave >> 1, wn = wave & 1;
  const int b = blockIdx.y;

  const int r = blockIdx.x & 7, w = blockIdx.x >> 3;  // grid.x = 136 = 8*17
  const int code = PAIR_LUT[r * 17 + w];
  const int qt = code >> 4, kt = code & 15;

  const long rowQ = (long)b * 2048 + (long)qt * 128;
  const long rowK = (long)b * 2048 + (long)kt * 128;

  floatx4 acc[4][4];
  const floatx4 zero = {0.f, 0.f, 0.f, 0.f};
#pragma unroll
  for (int i = 0; i < 4; ++i)
#pragma unroll
    for (int j = 0; j < 4; ++j) acc[i][j] = zero;

  // prologue: t0 -> buf0, t1 -> buf1; keep t1's 8 loads in flight
  stage128x64(Q, rowQ, 1024, 0, lds, lane, wave);
  stage128x64(Kk, rowK, 1024, 0, lds + 8192, lane, wave);
  stage128x64(Q, rowQ, 1024, 64, lds + 16384, lane, wave);
  stage128x64(Kk, rowK, 1024, 64, lds + 24576, lane, wave);
  asm volatile("s_waitcnt vmcnt(8)" ::: "memory");
  SBAR();

  for (int it = 0; it < 16; ++it) {
    const short* lA = lds + (it & 1) * 16384;
    const short* lB = lA + 8192;
    short8 a[4][2], bb[4][2];
#pragma unroll
    for (int i = 0; i < 4; ++i) a[i][0] = lds_rd(lA, wm * 64 + i * 16, 0, lane);
#pragma unroll
    for (int i = 0; i < 4; ++i) bb[i][0] = lds_rd(lB, wn * 64 + i * 16, 0, lane);
#pragma unroll
    for (int i = 0; i < 4; ++i) a[i][1] = lds_rd(lA, wm * 64 + i * 16, 32, lane);
#pragma unroll
    for (int i = 0; i < 4; ++i) bb[i][1] = lds_rd(lB, wn * 64 + i * 16, 32, lane);
    asm volatile("s_waitcnt lgkmcnt(8)" ::: "memory");  // k0 frags ready; k1 in flight
    SCHEDB();
    __builtin_amdgcn_s_setprio(1);
#pragma unroll
    for (int i = 0; i < 4; ++i)
#pragma unroll
      for (int j = 0; j < 4; ++j)
        acc[i][j] = __builtin_amdgcn_mfma_f32_16x16x32_bf16(a[i][0], bb[j][0], acc[i][j], 0, 0, 0);
    asm volatile("s_waitcnt lgkmcnt(0)" ::: "memory");
    SCHEDB();
#pragma unroll
    for (int i = 0; i < 4; ++i)
#pragma unroll
      for (int j = 0; j < 4; ++j)
        acc[i][j] = __builtin_amdgcn_mfma_f32_16x16x32_bf16(a[i][1], bb[j][1], acc[i][j], 0, 0, 0);
    __builtin_amdgcn_s_setprio(0);
    SBAR();                                   // all waves done reading this buf
    if (it + 2 < 16) {
      short* dst = lds + (it & 1) * 16384;
      stage128x64(Q, rowQ, 1024, (it + 2) * 64, dst, lane, wave);
      stage128x64(Kk, rowK, 1024, (it + 2) * 64, dst + 8192, lane, wave);
      asm volatile("s_waitcnt vmcnt(8)" ::: "memory");  // drain t+1 (issued 1 tile ago)
    } else {
      asm volatile("s_waitcnt vmcnt(0)" ::: "memory");
    }
    SBAR();
  }

  // epilogue (unchanged): exp + swizzled LDS E tile + row sums; reuse lds[0:16384)
  short* lbuf = lds;
  float* lrow = l + (long)b * 2048;
#pragma unroll
  for (int i = 0; i < 4; ++i) {
#pragma unroll
    for (int rr = 0; rr < 4; ++rr) {
      int ri = wm * 64 + i * 16 + (lane >> 4) * 4 + rr;
      int qrow = qt * 128 + ri;
      float psum = 0.f;
#pragma unroll
      for (int j = 0; j < 4; ++j) {
        int ci = wn * 64 + j * 16 + (lane & 15);
        int col = kt * 128 + ci;
        float sc = acc[i][j][rr] * 0.03125f;  // 1/sqrt(1024)
        float e = (col <= qrow) ? __expf(sc) : 0.0f;
        short eb = f2bf(e);
        lbuf[ri * 128 + ((((ci >> 3) ^ (ri & 15)) << 3) | (ci & 7))] = eb;
        psum += bf2f(eb);
      }
      for (int m = 1; m < 16; m <<= 1) psum += __shfl_xor(psum, m, 64);
      if ((lane & 15) == 0) atomicAdd(&lrow[qrow], psum);
    }
  }
  __syncthreads();

  short* Eb = E + (long)b * 4194304;
  const long ebase = (long)(qt * 128) * 2048 + kt * 128;
#pragma unroll
  for (int pp = 0; pp < 8; ++pp) {
    int g = pp * 256 + threadIdx.x;
    int row = g >> 4, c = g & 15;
    short8 v = *(const short8*)(lbuf + row * 128 + ((c ^ (row & 15)) << 3));
    *(short8*)(Eb + ebase + (long)row * 2048 + c * 8) = v;
  }
}

// ============================================================================
// stage 3 (r7): O = (E @ V) / l — same depth-2 DBUF pipeline, with guards for
// the variable [it0,it1) span (span>=2 everywhere except audited qt=0 case).
// ============================================================================
__global__ __launch_bounds__(256, 2) void pv_gemm(const short* __restrict__ E,
                                                  const short* __restrict__ Vt,
                                                  const float* __restrict__ l,
                                                  float* __restrict__ part,
                                                  float* __restrict__ out) {
  __shared__ __align__(16) short lds[32768];  // [buf][{E,V}][8192]
  const int lane = threadIdx.x & 63, wave = threadIdx.x >> 6;
  const int wm = wave >> 1, wn = wave & 1;
  const int xx = blockIdx.x;            // [0,192)
  const int dt = xx / 24;
  const int within = xx % 24;
  const int r = within & 7, wsel = within >> 3;  // wsel in {0,1,2}
  const int b = blockIdx.y;

  int qt, it0, it1, mode;  // mode: 0 direct(/l), 1 chunk0->out raw, 2 chunk1->part raw
  if (wsel == 2) {
    qt = r; it0 = 0; it1 = (qt + 1) * 2; mode = 0;
  } else {
    qt = 15 - r;
    const int T = (qt + 1) * 2, c0 = T >> 1;
    if (wsel == 0) { it0 = 0;  it1 = c0; mode = 1; }
    else           { it0 = c0; it1 = T;  mode = 2; }
  }

  const short* Eb = E + (long)b * 2048 * 2048;
  const short* Vb = Vt + (long)b * 1024 * 2048;
  const float* lrow = l + (long)b * 2048;
  const long rowE = (long)qt * 128, rowV = (long)dt * 128;

  floatx4 acc[4][4];
  const floatx4 zero = {0.f, 0.f, 0.f, 0.f};
#pragma unroll
  for (int i = 0; i < 4; ++i)
#pragma unroll
    for (int j = 0; j < 4; ++j) acc[i][j] = zero;

  // prologue: it0 -> buf0; it0+1 -> buf1 (if it exists)
  stage128x64(Eb, rowE, 2048, it0 * 64, lds, lane, wave);
  stage128x64(Vb, rowV, 2048, it0 * 64, lds + 8192, lane, wave);
  if (it0 + 1 < it1) {
    stage128x64(Eb, rowE, 2048, (it0 + 1) * 64, lds + 16384, lane, wave);
    stage128x64(Vb, rowV, 2048, (it0 + 1) * 64, lds + 24576, lane, wave);
    asm volatile("s_waitcnt vmcnt(8)" ::: "memory");
  } else {
    asm volatile("s_waitcnt vmcnt(0)" ::: "memory");
  }
  SBAR();

  for (int it = it0; it < it1; ++it) {
    const short* lA = lds + ((it - it0) & 1) * 16384;
    const short* lB = lA + 8192;
    short8 a[4][2], bb[4][2];
#pragma unroll
    for (int i = 0; i < 4; ++i) a[i][0] = lds_rd(lA, wm * 64 + i * 16, 0, lane);
#pragma unroll
    for (int i = 0; i < 4; ++i) bb[i][0] = lds_rd(lB, wn * 64 + i * 16, 0, lane);
#pragma unroll
    for (int i = 0; i < 4; ++i) a[i][1] = lds_rd(lA, wm * 64 + i * 16, 32, lane);
#pragma unroll
    for (int i = 0; i < 4; ++i) bb[i][1] = lds_rd(lB, wn * 64 + i * 16, 32, lane);
    asm volatile("s_waitcnt lgkmcnt(8)" ::: "memory");
    SCHEDB();
    __builtin_amdgcn_s_setprio(1);
#pragma unroll
    for (int i = 0; i < 4; ++i)
#pragma unroll
      for (int j = 0; j < 4; ++j)
        acc[i][j] = __builtin_amdgcn_mfma_f32_16x16x32_bf16(a[i][0], bb[j][0], acc[i][j], 0, 0, 0);
    asm volatile("s_waitcnt lgkmcnt(0)" ::: "memory");
    SCHEDB();
#pragma unroll
    for (int i = 0; i < 4; ++i)
#pragma unroll
      for (int j = 0; j < 4; ++j)
        acc[i][j] = __builtin_amdgcn_mfma_f32_16x16x32_bf16(a[i][1], bb[j][1], acc[i][j], 0, 0, 0);
    __builtin_amdgcn_s_setprio(0);
    SBAR();
    if (it + 2 < it1) {
      short* dst = lds + ((it - it0) & 1) * 16384;
      stage128x64(Eb, rowE, 2048, (it + 2) * 64, dst, lane, wave);
      stage128x64(Vb, rowV, 2048, (it + 2) * 64, dst + 8192, lane, wave);
      asm volatile("s_waitcnt vmcnt(8)" ::: "memory");
    } else {
      asm volatile("s_waitcnt vmcnt(0)" ::: "memory");
    }
    SBAR();
  }

  if (mode == 2) {
    float* P = part + ((((long)b * 8 + (qt - 8)) * 8 + dt) << 14);
#pragma unroll
    for (int i = 0; i < 4; ++i)
#pragma unroll
      for (int rr = 0; rr < 4; ++rr) {
        int ri = wm * 64 + i * 16 + (lane >> 4) * 4 + rr;
#pragma unroll
        for (int j = 0; j < 4; ++j) {
          int ci = wn * 64 + j * 16 + (lane & 15);
          P[ri * 128 + ci] = acc[i][j][rr];
        }
      }
  } else {
#pragma unroll
    for (int i = 0; i < 4; ++i)
#pragma unroll
      for (int rr = 0; rr < 4; ++rr) {
        int qrow = qt * 128 + wm * 64 + i * 16 + (lane >> 4) * 4 + rr;
        float scale = (mode == 0) ? 1.0f / lrow[qrow] : 1.0f;
#pragma unroll
        for (int j = 0; j < 4; ++j) {
          int d = dt * 128 + wn * 64 + j * 16 + (lane & 15);
          out[((long)b * 2048 + qrow) * 1024 + d] = acc[i][j][rr] * scale;
        }
      }
  }
}

// ---- stage 4: rows qt>=8: out = (out + part)/l ----
__global__ void pv_reduce(float* __restrict__ out, const float* __restrict__ part,
                          const float* __restrict__ l) {
  const int idx = blockIdx.x;           // 4096 = 4b * 1024 rows
  const int b = idx >> 10;
  const int row = 1024 + (idx & 1023);  // global row in [1024, 2048)
  const int t = threadIdx.x;
  const int dt = t >> 5, dl = (t << 2) & 127;
  const float inv = 1.0f / l[((long)b << 11) + row];
  const long pbase = ((((long)b * 8 + ((row >> 7) - 8)) * 8 + dt) << 14) + ((row & 127) << 7) + dl;
  const long obase = (((long)b * 2048 + row) << 10) + (t << 2);
  float4 o = *(const float4*)(out + obase);
  float4 p = *(const float4*)(part + pbase);
  o.x = (o.x + p.x) * inv; o.y = (o.y + p.y) * inv;
  o.z = (o.z + p.z) * inv; o.w = (o.w + p.w) * inv;
  *(float4*)(out + obase) = o;
}

extern "C" void kernel_launch(void* const* d_in, const int* in_sizes, int n_in,
                              void* d_out, int out_size, void* d_ws, size_t ws_size,
                              hipStream_t stream) {
  const float* X  = (const float*)d_in[0];
  const float* Wq = (const float*)d_in[1];
  const float* Wk = (const float*)d_in[2];
  const float* Wv = (const float*)d_in[3];

  char* ws = (char*)d_ws;
  // layout (bytes): Xb 16M (reused as pv partials) | Wt 6M | Q 16M | K 16M | Vt 16M | E 32M | l 32K
  short* Xb = (short*)(ws);
  short* Wt = (short*)(ws + 16777216L);
  short* Q  = (short*)(ws + 23068672L);
  short* K2 = (short*)(ws + 39845888L);
  short* Vt = (short*)(ws + 56623104L);
  short* E  = (short*)(ws + 73400320L);
  float* l  = (float*)(ws + 106954752L);
  float* part = (float*)(ws);  // 256 tiles * 64KB = 16MB, overlays dead Xb

  prep_inputs<<<11296, 256, 0, stream>>>(X, Wq, Wk, Wv, Xb, Wt, l);
  gemm_qkv<<<384, 512, 0, stream>>>(Xb, Wt, Q, K2, Vt);
  scores_exp<<<dim3(136, 4), 256, 0, stream>>>(Q, K2, E, l);
  pv_gemm<<<dim3(192, 4), 256, 0, stream>>>(E, Vt, l, part, (float*)d_out);
  pv_reduce<<<4096, 256, 0, stream>>>((float*)d_out, part, l);
}

// Round 8
// 229.570 us; speedup vs baseline: 1.0332x; 1.0305x over previous
//
#include <hip/hip_runtime.h>

#define AS1 __attribute__((address_space(1)))
#define AS3 __attribute__((address_space(3)))

typedef __attribute__((ext_vector_type(8))) short short8;
typedef __attribute__((ext_vector_type(4))) float floatx4;

// ---- bf16 helpers (RNE; inputs are finite, no NaN/Inf handling needed) ----
__device__ __forceinline__ short f2bf(float f) {
  union { float f; unsigned u; } v; v.f = f;
  return (short)((v.u + 0x7fffu + ((v.u >> 16) & 1u)) >> 16);
}
__device__ __forceinline__ float bf2f(short s) {
  union { unsigned u; float f; } v; v.u = ((unsigned)(unsigned short)s) << 16;
  return v.f;
}

// ---- async global->LDS, 16B per lane (wave-uniform LDS base + lane*16) ----
__device__ __forceinline__ void gload_lds16(const void* g, void* l) {
  __builtin_amdgcn_global_load_lds((const AS1 unsigned*)g, (AS3 unsigned*)l, 16, 0, 0);
}

// Stage a 128x64 bf16 tile of row-major G into 128x64 LDS with XOR-swizzled
// chunk layout (source chunk = (lane&7) ^ (row&7); LDS dest linear, rule #21).
// 256 threads / 4 waves; 4 gloads per thread.
__device__ __forceinline__ void stage128x64(const short* __restrict__ G, long rowBase, long ld,
                                            int kBase, short* lds, int lane, int wave) {
  const int chunk = (lane & 7) ^ ((lane >> 3) & 7);
  const short* gb = G + rowBase * ld + (long)kBase + (long)(lane >> 3) * ld + chunk * 8;
#pragma unroll
  for (int j = 0; j < 4; ++j) {
    int c = wave * 4 + j;
    gload_lds16(gb + (long)c * 8 * ld, lds + c * 512);
  }
}

// Swizzled ds_read_b128 of one MFMA fragment (matches stage128x64 / stage_half
// source swizzle): row multiple of 16; col = kq ^ ((lane&7)<<3).
__device__ __forceinline__ short8 lds_rd(const short* l, int row, int kk, int lane) {
  const int r = row + (lane & 15);
  const int c = (kk + ((lane >> 4) << 3)) ^ ((lane & 7) << 3);
  return *(const short8*)(l + r * 64 + c);
}

#define MEMFENCE() asm volatile("" ::: "memory")
#define SBAR() do { MEMFENCE(); __builtin_amdgcn_s_barrier(); MEMFENCE(); } while (0)
#define SCHEDB() __builtin_amdgcn_sched_barrier(0)

// r8: kt-PAIRED causal LUT. Entry = (qt<<4)|ktp; block computes kt0=2*ktp and
// (if kt1=2*ktp+1 <= qt) kt1, sharing the staged Q slice -> Q traffic halved.
// qt-major enumeration, 72 entries = 8 classes x 9 (class = blockIdx.x&7,
// entry = class*9 + (blockIdx.x>>3)); contiguous qt per class for L2 overlap.
__device__ const unsigned char PAIR72[72] = {
  0x00,
  0x10,
  0x20,0x21,
  0x30,0x31,
  0x40,0x41,0x42,
  0x50,0x51,0x52,
  0x60,0x61,0x62,0x63,
  0x70,0x71,0x72,0x73,
  0x80,0x81,0x82,0x83,0x84,
  0x90,0x91,0x92,0x93,0x94,
  0xA0,0xA1,0xA2,0xA3,0xA4,0xA5,
  0xB0,0xB1,0xB2,0xB3,0xB4,0xB5,
  0xC0,0xC1,0xC2,0xC3,0xC4,0xC5,0xC6,
  0xD0,0xD1,0xD2,0xD3,0xD4,0xD5,0xD6,
  0xE0,0xE1,0xE2,0xE3,0xE4,0xE5,0xE6,0xE7,
  0xF0,0xF1,0xF2,0xF3,0xF4,0xF5,0xF6,0xF7
};

// ---- stage 0 (fused): [0,8192) convert X; [8192,11264) transpose W; [11264,11296) zero l ----
__global__ void prep_inputs(const float* __restrict__ X, const float* __restrict__ Wq,
                            const float* __restrict__ Wk, const float* __restrict__ Wv,
                            short* __restrict__ Xb, short* __restrict__ Wt,
                            float* __restrict__ l) {
  __shared__ float t[32][33];
  if (blockIdx.x < 8192) {
    long i = ((long)blockIdx.x * 256 + threadIdx.x) * 4;
    float4 v = *(const float4*)(X + i);
    short4 o;
    o.x = f2bf(v.x); o.y = f2bf(v.y); o.z = f2bf(v.z); o.w = f2bf(v.w);
    *(short4*)(Xb + i) = o;
  } else if (blockIdx.x < 11264) {
    int idx = blockIdx.x - 8192;           // [0,3072): z*1024 + bx*32 + by
    int z = idx >> 10, rem = idx & 1023;
    int bx = rem >> 5, by = rem & 31;
    const float* W = z == 0 ? Wq : (z == 1 ? Wk : Wv);
    short* O = Wt + (long)z * 1024 * 1024;
    int tx = threadIdx.x & 31, ty = threadIdx.x >> 5;
    int x = bx * 32 + tx;
    int y0 = by * 32;
    for (int j = ty; j < 32; j += 8)
      t[j][tx] = W[(long)(y0 + j) * 1024 + x];
    __syncthreads();
    int x2 = by * 32 + tx;
    int y2 = bx * 32;
    for (int j = ty; j < 32; j += 8)
      O[(long)(y2 + j) * 1024 + x2] = f2bf(t[tx][j]);
  } else {
    l[(blockIdx.x - 11264) * 256 + threadIdx.x] = 0.0f;
  }
}

// ============================================================================
// stage 1: Q/K/V = X @ W — 256x256 tile, BK=64, 8 waves, 4-phase/K-tile with
// ONE-PHASE-AHEAD register pipelining (r5, frozen — best measured 65.7us).
// ============================================================================
#define LOFF(b, m, h) ((((b) * 2 + (m)) * 2 + (h)) * 8192)

// Stage one 128x64 half-tile with 512 threads (2 x global_load_lds each).
// Source chunk pre-swizzled: chunk = (tid&7) ^ ((tid>>3)&7); LDS dest linear.
__device__ __forceinline__ void stage_half(const short* __restrict__ g, short* l, int wv) {
  gload_lds16(g, l + wv * 512);                    // rows 0..63   (chunk j=0)
  gload_lds16(g + 65536, l + 4096 + wv * 512);     // rows 64..127 (chunk j=1)
}

__global__ __launch_bounds__(512, 2) void gemm_qkv(const short* __restrict__ Xb,
                                                   const short* __restrict__ Wt,
                                                   short* __restrict__ Q, short* __restrict__ K2,
                                                   short* __restrict__ Vt) {
  // [buf][mat A=0/B=1][half][128*64] = 128 KiB
  __shared__ __align__(16) short lds[65536];
  const int tid = threadIdx.x;
  const int lane = tid & 63, wv = tid >> 6;
  const int wm = wv >> 2, wn = wv & 3;   // 2 x 4 wave grid; per-wave C = 128x64

  // T1: XCD-chunked mapping (384 = 8 XCDs * 48), ng-fastest.
  const int bid = blockIdx.x;
  const int xcd = bid & 7, w = bid >> 3;           // w in [0,48)
  const int mt = xcd * 4 + (w / 12);               // [0,32)
  const int ng = w % 12;                           // z*4 + n_tile
  const int z = ng >> 2;
  const long mBase = (long)mt * 256;
  const long nBase = (long)(ng & 3) * 256;
  const short* Bm = Wt + (long)z * 1048576;

  // per-thread staging source (pre-swizzled column chunk)
  const int r0 = tid >> 3;                          // 0..63
  const int cc = ((tid & 7) ^ (r0 & 7)) << 3;       // element offset, 16B chunk
  const short* gA = Xb + (mBase + r0) * 1024 + cc;
  const short* gB = Bm + (nBase + r0) * 1024 + cc;

  floatx4 acc[8][4];
  const floatx4 zero = {0.f, 0.f, 0.f, 0.f};
#pragma unroll
  for (int i = 0; i < 8; ++i)
#pragma unroll
    for (int j = 0; j < 4; ++j) acc[i][j] = zero;

  short8 a0[4][2], a1[4][2], bq[2][2];   // live across tiles (software pipeline)

  // ---- prologue ----
  stage_half(gA, lds + LOFF(0, 0, 0), wv);
  stage_half(gA + 131072, lds + LOFF(0, 0, 1), wv);
  stage_half(gB, lds + LOFF(0, 1, 0), wv);
  stage_half(gB + 131072, lds + LOFF(0, 1, 1), wv);
  stage_half(gA + 64, lds + LOFF(1, 0, 0), wv);
  stage_half(gA + 64 + 131072, lds + LOFF(1, 0, 1), wv);
  stage_half(gB + 64, lds + LOFF(1, 1, 0), wv);
  asm volatile("s_waitcnt vmcnt(6)" ::: "memory");  // A(0),B(0) resident; 3 half-tiles in flight
  SBAR();
  {
    const short* Ab0 = lds + LOFF(0, 0, wm);
#pragma unroll
    for (int f = 0; f < 4; ++f) a0[f][0] = lds_rd(Ab0, f * 16, 0, lane);
#pragma unroll
    for (int f = 0; f < 4; ++f) a0[f][1] = lds_rd(Ab0, f * 16, 32, lane);
  }

#pragma unroll 2
  for (int t = 0; t < 16; ++t) {
    const int buf = t & 1;
    const short* Ab  = lds + LOFF(buf, 0, wm);        // this wave's A half
    const short* Bb  = lds + LOFF(buf, 1, (wn >> 1)); // this wave's B half
    const short* AbN = lds + LOFF(buf ^ 1, 0, wm);    // next tile's A half
    const int brow = (wn & 1) * 64;

    // ---- ph1: rd b0->bq + a1; stage B(t+1).h1; lgkm(8); MFMA a0 x b0 ----
    bq[0][0] = lds_rd(Bb, brow, 0, lane);
    bq[1][0] = lds_rd(Bb, brow + 16, 0, lane);
    bq[0][1] = lds_rd(Bb, brow, 32, lane);
    bq[1][1] = lds_rd(Bb, brow + 16, 32, lane);
#pragma unroll
    for (int f = 0; f < 4; ++f) a1[f][0] = lds_rd(Ab, 64 + f * 16, 0, lane);
#pragma unroll
    for (int f = 0; f < 4; ++f) a1[f][1] = lds_rd(Ab, 64 + f * 16, 32, lane);
    if (t < 15) stage_half(gB + (t + 1) * 64 + 131072, lds + LOFF(buf ^ 1, 1, 1), wv);
    asm volatile("s_waitcnt lgkmcnt(8)" ::: "memory");  // a0,b0 ready; a1 in flight
    SCHEDB();
    __builtin_amdgcn_s_setprio(1);
#pragma unroll
    for (int f = 0; f < 4; ++f)
#pragma unroll
      for (int n = 0; n < 2; ++n)
        acc[f][n] = __builtin_amdgcn_mfma_f32_16x16x32_bf16(a0[f][0], bq[n][0], acc[f][n], 0, 0, 0);
#pragma unroll
    for (int f = 0; f < 4; ++f)
#pragma unroll
      for (int n = 0; n < 2; ++n)
        acc[f][n] = __builtin_amdgcn_mfma_f32_16x16x32_bf16(a0[f][1], bq[n][1], acc[f][n], 0, 0, 0);
    __builtin_amdgcn_s_setprio(0);

    // ---- ph2: a1 drained under ph1 MFMA; MFMA a1 x b0; BAR ----
    asm volatile("s_waitcnt lgkmcnt(0)" ::: "memory");
    SCHEDB();
    __builtin_amdgcn_s_setprio(1);
#pragma unroll
    for (int f = 0; f < 4; ++f)
#pragma unroll
      for (int n = 0; n < 2; ++n)
        acc[4 + f][n] = __builtin_amdgcn_mfma_f32_16x16x32_bf16(a1[f][0], bq[n][0], acc[4 + f][n], 0, 0, 0);
#pragma unroll
    for (int f = 0; f < 4; ++f)
#pragma unroll
      for (int n = 0; n < 2; ++n)
        acc[4 + f][n] = __builtin_amdgcn_mfma_f32_16x16x32_bf16(a1[f][1], bq[n][1], acc[4 + f][n], 0, 0, 0);
    __builtin_amdgcn_s_setprio(0);
    SBAR();   // all A(t)/b0 reads done chip-wide -> A-region staging safe

    // ---- ph3: rd b1->bq; stage A(t+2).h0; lgkm(0); MFMA a0 x b1; vmcnt; BAR ----
    bq[0][0] = lds_rd(Bb, brow + 32, 0, lane);
    bq[1][0] = lds_rd(Bb, brow + 48, 0, lane);
    bq[0][1] = lds_rd(Bb, brow + 32, 32, lane);
    bq[1][1] = lds_rd(Bb, brow + 48, 32, lane);
    if (t < 14) stage_half(gA + (t + 2) * 64, lds + LOFF(buf, 0, 0), wv);
    asm volatile("s_waitcnt lgkmcnt(0)" ::: "memory");
    SCHEDB();
    __builtin_amdgcn_s_setprio(1);
#pragma unroll
    for (int f = 0; f < 4; ++f)
#pragma unroll
      for (int n = 0; n < 2; ++n)
        acc[f][2 + n] = __builtin_amdgcn_mfma_f32_16x16x32_bf16(a0[f][0], bq[n][0], acc[f][2 + n], 0, 0, 0);
#pragma unroll
    for (int f = 0; f < 4; ++f)
#pragma unroll
      for (int n = 0; n < 2; ++n)
        acc[f][2 + n] = __builtin_amdgcn_mfma_f32_16x16x32_bf16(a0[f][1], bq[n][1], acc[f][2 + n], 0, 0, 0);
    __builtin_amdgcn_s_setprio(0);
    if (t < 14) { asm volatile("s_waitcnt vmcnt(2)" ::: "memory"); }
    else        { asm volatile("s_waitcnt vmcnt(0)" ::: "memory"); }
    SBAR();   // A(t+1),B(t+1) resident chip-wide; b-reads of tile t done

    // ---- ph4: rd a0'(next tile); stage A(t+2).h1 + B(t+2).h0; MFMA a1 x b1 ----
    if (t < 15) {
#pragma unroll
      for (int f = 0; f < 4; ++f) a0[f][0] = lds_rd(AbN, f * 16, 0, lane);
#pragma unroll
      for (int f = 0; f < 4; ++f) a0[f][1] = lds_rd(AbN, f * 16, 32, lane);
    }
    if (t < 14) {
      stage_half(gA + (t + 2) * 64 + 131072, lds + LOFF(buf, 0, 1), wv);
      stage_half(gB + (t + 2) * 64, lds + LOFF(buf, 1, 0), wv);
    }
    SCHEDB();   // pin a0' issue + staging BEFORE the MFMA cluster
    __builtin_amdgcn_s_setprio(1);
#pragma unroll
    for (int f = 0; f < 4; ++f)
#pragma unroll
      for (int n = 0; n < 2; ++n)
        acc[4 + f][2 + n] = __builtin_amdgcn_mfma_f32_16x16x32_bf16(a1[f][0], bq[n][0], acc[4 + f][2 + n], 0, 0, 0);
#pragma unroll
    for (int f = 0; f < 4; ++f)
#pragma unroll
      for (int n = 0; n < 2; ++n)
        acc[4 + f][2 + n] = __builtin_amdgcn_mfma_f32_16x16x32_bf16(a1[f][1], bq[n][1], acc[4 + f][2 + n], 0, 0, 0);
    __builtin_amdgcn_s_setprio(0);
  }

  // ---- epilogue ----
  if (z < 2) {
    short* outp = (z == 0) ? Q : K2;
#pragma unroll
    for (int f = 0; f < 8; ++f)
#pragma unroll
      for (int n = 0; n < 4; ++n) {
        const int col = (int)nBase + wn * 64 + n * 16 + (lane & 15);
#pragma unroll
        for (int rr = 0; rr < 4; ++rr) {
          const long m = mBase + wm * 128 + f * 16 + ((lane >> 4) << 2) + rr;
          outp[m * 1024 + col] = f2bf(acc[f][n][rr]);
        }
      }
  } else {
    // V transposed write: in Vt[b][d][s], the 4 r-values are s-contiguous
    const long bz = mBase >> 11;
    const int sB = (int)(mBase & 2047);
#pragma unroll
    for (int f = 0; f < 8; ++f) {
      const int s0 = sB + wm * 128 + f * 16 + ((lane >> 4) << 2);
#pragma unroll
      for (int n = 0; n < 4; ++n) {
        const int col = (int)nBase + wn * 64 + n * 16 + (lane & 15);
        short4 o;
        o.x = f2bf(acc[f][n][0]); o.y = f2bf(acc[f][n][1]);
        o.z = f2bf(acc[f][n][2]); o.w = f2bf(acc[f][n][3]);
        *(short4*)(Vt + ((bz * 1024 + col) * 2048 + s0)) = o;
      }
    }
  }
}

// ============================================================================
// stage 2 (r8): E = exp(Q K^T / 32), kt-PAIRED — one block computes (qt,kt0)
// and (qt,kt1=kt0+1 if <=qt), sharing the staged Q slice (Q traffic halved;
// scores was L3-BW-bound, not schedule-bound: r6/r7 scheduling changes null).
// Serial single-buffer staging (proven-correct structure); 48 KB LDS,
// 2 blocks/CU. Per-acc MFMA order unchanged -> bit-identical E and l.
// ============================================================================
__global__ __launch_bounds__(256, 2) void scores_exp(const short* __restrict__ Q,
                                                     const short* __restrict__ Kk,
                                                     short* __restrict__ E, float* __restrict__ l) {
  __shared__ __align__(16) short lds[24576];  // lQ | lK0 | lK1 ; epilogue reuses [0:16384)
  short* lQ = lds;
  short* lK0 = lds + 8192;
  short* lK1 = lds + 16384;
  const int lane = threadIdx.x & 63, wave = threadIdx.x >> 6;
  const int wm = wave >> 1, wn = wave & 1;
  const int b = blockIdx.y;

  const int cls = blockIdx.x & 7, idx = blockIdx.x >> 3;  // grid.x = 72 = 8*9
  const int code = PAIR72[cls * 9 + idx];
  const int qt = code >> 4, ktp = code & 15;
  const int kt0 = ktp * 2, kt1 = kt0 + 1;
  const bool two = (kt1 <= qt);

  const long rowQ = (long)b * 2048 + (long)qt * 128;
  const long rowK0 = (long)b * 2048 + (long)kt0 * 128;
  const long rowK1 = rowK0 + 128;

  floatx4 acc0[4][4], acc1[4][4];
  const floatx4 zero = {0.f, 0.f, 0.f, 0.f};
#pragma unroll
  for (int i = 0; i < 4; ++i)
#pragma unroll
    for (int j = 0; j < 4; ++j) { acc0[i][j] = zero; acc1[i][j] = zero; }

  for (int it = 0; it < 16; ++it) {
    stage128x64(Q, rowQ, 1024, it * 64, lQ, lane, wave);
    stage128x64(Kk, rowK0, 1024, it * 64, lK0, lane, wave);
    if (two) stage128x64(Kk, rowK1, 1024, it * 64, lK1, lane, wave);
    __syncthreads();
    short8 a[4][2], bb[4][2];
#pragma unroll
    for (int i = 0; i < 4; ++i) {
      a[i][0] = lds_rd(lQ, wm * 64 + i * 16, 0, lane);
      a[i][1] = lds_rd(lQ, wm * 64 + i * 16, 32, lane);
    }
#pragma unroll
    for (int i = 0; i < 4; ++i) {
      bb[i][0] = lds_rd(lK0, wn * 64 + i * 16, 0, lane);
      bb[i][1] = lds_rd(lK0, wn * 64 + i * 16, 32, lane);
    }
#pragma unroll
    for (int ks = 0; ks < 2; ++ks)
#pragma unroll
      for (int i = 0; i < 4; ++i)
#pragma unroll
        for (int j = 0; j < 4; ++j)
          acc0[i][j] = __builtin_amdgcn_mfma_f32_16x16x32_bf16(a[i][ks], bb[j][ks], acc0[i][j], 0, 0, 0);
    if (two) {
#pragma unroll
      for (int i = 0; i < 4; ++i) {
        bb[i][0] = lds_rd(lK1, wn * 64 + i * 16, 0, lane);
        bb[i][1] = lds_rd(lK1, wn * 64 + i * 16, 32, lane);
      }
#pragma unroll
      for (int ks = 0; ks < 2; ++ks)
#pragma unroll
        for (int i = 0; i < 4; ++i)
#pragma unroll
          for (int j = 0; j < 4; ++j)
            acc1[i][j] = __builtin_amdgcn_mfma_f32_16x16x32_bf16(a[i][ks], bb[j][ks], acc1[i][j], 0, 0, 0);
    }
    __syncthreads();
  }

  // epilogue per kt tile: fill swizzled E tile in LDS + row sums, then store.
  short* lbuf = lds;
  float* lrow = l + (long)b * 2048;
  short* Eb = E + (long)b * 4194304;
#pragma unroll 1
  for (int tsel = 0; tsel < 2; ++tsel) {
    if (tsel == 1 && !two) break;
    const int kt = tsel == 0 ? kt0 : kt1;
    floatx4 (&acc)[4][4] = tsel == 0 ? acc0 : acc1;
    if (tsel == 1) __syncthreads();  // prior E-store reads of lbuf complete
#pragma unroll
    for (int i = 0; i < 4; ++i) {
#pragma unroll
      for (int rr = 0; rr < 4; ++rr) {
        int ri = wm * 64 + i * 16 + (lane >> 4) * 4 + rr;
        int qrow = qt * 128 + ri;
        float psum = 0.f;
#pragma unroll
        for (int j = 0; j < 4; ++j) {
          int ci = wn * 64 + j * 16 + (lane & 15);
          int col = kt * 128 + ci;
          float sc = acc[i][j][rr] * 0.03125f;  // 1/sqrt(1024)
          float e = (col <= qrow) ? __expf(sc) : 0.0f;
          short eb = f2bf(e);
          lbuf[ri * 128 + ((((ci >> 3) ^ (ri & 15)) << 3) | (ci & 7))] = eb;
          psum += bf2f(eb);
        }
        for (int m = 1; m < 16; m <<= 1) psum += __shfl_xor(psum, m, 64);
        if ((lane & 15) == 0) atomicAdd(&lrow[qrow], psum);
      }
    }
    __syncthreads();
    const long ebase = (long)(qt * 128) * 2048 + kt * 128;
#pragma unroll
    for (int pp = 0; pp < 8; ++pp) {
      int g = pp * 256 + threadIdx.x;
      int row = g >> 4, c = g & 15;
      short8 v = *(const short8*)(lbuf + row * 128 + ((c ^ (row & 15)) << 3));
      *(short8*)(Eb + ebase + (long)row * 2048 + c * 8) = v;
    }
  }
}

// ============================================================================
// stage 3 (r8): O = (E @ V) / l, dt-PAIRED (dt and dt+4 share the staged E
// slice -> E L3-traffic halved) + dt-pair-per-XCD-pair mapping (V panels
// 1 MB -> L2-resident; V L3-reads ~= unique only). Split-K wsel/mode logic
// unchanged; per-acc MFMA order unchanged -> bit-identical output.
// Grid (96, 4): xcd = x&7, dtp = xcd>>1, within = (xcd&1)*12 + (x>>3).
// ============================================================================
__global__ __launch_bounds__(256, 2) void pv_gemm(const short* __restrict__ E,
                                                  const short* __restrict__ Vt,
                                                  const float* __restrict__ l,
                                                  float* __restrict__ part,
                                                  float* __restrict__ out) {
  __shared__ __align__(16) short lds[24576];  // lE | lV0 | lV1
  short* lE = lds;
  short* lV0 = lds + 8192;
  short* lV1 = lds + 16384;
  const int lane = threadIdx.x & 63, wave = threadIdx.x >> 6;
  const int wm = wave >> 1, wn = wave & 1;
  const int x = blockIdx.x;              // [0,96)
  const int xcd = x & 7, w = x >> 3;     // w in [0,12)
  const int dt0 = xcd >> 1, dt1 = dt0 + 4;
  const int within = (xcd & 1) * 12 + w; // [0,24)
  const int r = within & 7, wsel = within >> 3;  // wsel in {0,1,2}
  const int b = blockIdx.y;

  int qt, it0, it1, mode;  // mode: 0 direct(/l), 1 chunk0->out raw, 2 chunk1->part raw
  if (wsel == 2) {
    qt = r; it0 = 0; it1 = (qt + 1) * 2; mode = 0;
  } else {
    qt = 15 - r;
    const int T = (qt + 1) * 2, c0 = T >> 1;
    if (wsel == 0) { it0 = 0;  it1 = c0; mode = 1; }
    else           { it0 = c0; it1 = T;  mode = 2; }
  }

  const short* Eb = E + (long)b * 2048 * 2048;
  const short* Vb = Vt + (long)b * 1024 * 2048;
  const float* lrow = l + (long)b * 2048;
  const long rowE = (long)qt * 128;
  const long rowV0 = (long)dt0 * 128, rowV1 = (long)dt1 * 128;

  floatx4 acc0[4][4], acc1[4][4];
  const floatx4 zero = {0.f, 0.f, 0.f, 0.f};
#pragma unroll
  for (int i = 0; i < 4; ++i)
#pragma unroll
    for (int j = 0; j < 4; ++j) { acc0[i][j] = zero; acc1[i][j] = zero; }

  for (int it = it0; it < it1; ++it) {
    stage128x64(Eb, rowE, 2048, it * 64, lE, lane, wave);
    stage128x64(Vb, rowV0, 2048, it * 64, lV0, lane, wave);
    stage128x64(Vb, rowV1, 2048, it * 64, lV1, lane, wave);
    __syncthreads();
    short8 a[4][2], bb[4][2];
#pragma unroll
    for (int i = 0; i < 4; ++i) {
      a[i][0] = lds_rd(lE, wm * 64 + i * 16, 0, lane);
      a[i][1] = lds_rd(lE, wm * 64 + i * 16, 32, lane);
    }
#pragma unroll
    for (int i = 0; i < 4; ++i) {
      bb[i][0] = lds_rd(lV0, wn * 64 + i * 16, 0, lane);
      bb[i][1] = lds_rd(lV0, wn * 64 + i * 16, 32, lane);
    }
#pragma unroll
    for (int ks = 0; ks < 2; ++ks)
#pragma unroll
      for (int i = 0; i < 4; ++i)
#pragma unroll
        for (int j = 0; j < 4; ++j)
          acc0[i][j] = __builtin_amdgcn_mfma_f32_16x16x32_bf16(a[i][ks], bb[j][ks], acc0[i][j], 0, 0, 0);
#pragma unroll
    for (int i = 0; i < 4; ++i) {
      bb[i][0] = lds_rd(lV1, wn * 64 + i * 16, 0, lane);
      bb[i][1] = lds_rd(lV1, wn * 64 + i * 16, 32, lane);
    }
#pragma unroll
    for (int ks = 0; ks < 2; ++ks)
#pragma unroll
      for (int i = 0; i < 4; ++i)
#pragma unroll
        for (int j = 0; j < 4; ++j)
          acc1[i][j] = __builtin_amdgcn_mfma_f32_16x16x32_bf16(a[i][ks], bb[j][ks], acc1[i][j], 0, 0, 0);
    __syncthreads();
  }

  if (mode == 2) {
    float* P0 = part + ((((long)b * 8 + (qt - 8)) * 8 + dt0) << 14);
    float* P1 = part + ((((long)b * 8 + (qt - 8)) * 8 + dt1) << 14);
#pragma unroll
    for (int i = 0; i < 4; ++i)
#pragma unroll
      for (int rr = 0; rr < 4; ++rr) {
        int ri = wm * 64 + i * 16 + (lane >> 4) * 4 + rr;
#pragma unroll
        for (int j = 0; j < 4; ++j) {
          int ci = wn * 64 + j * 16 + (lane & 15);
          P0[ri * 128 + ci] = acc0[i][j][rr];
          P1[ri * 128 + ci] = acc1[i][j][rr];
        }
      }
  } else {
#pragma unroll
    for (int i = 0; i < 4; ++i)
#pragma unroll
      for (int rr = 0; rr < 4; ++rr) {
        int qrow = qt * 128 + wm * 64 + i * 16 + (lane >> 4) * 4 + rr;
        float scale = (mode == 0) ? 1.0f / lrow[qrow] : 1.0f;
#pragma unroll
        for (int j = 0; j < 4; ++j) {
          int ci = wn * 64 + j * 16 + (lane & 15);
          out[((long)b * 2048 + qrow) * 1024 + dt0 * 128 + ci] = acc0[i][j][rr] * scale;
          out[((long)b * 2048 + qrow) * 1024 + dt1 * 128 + ci] = acc1[i][j][rr] * scale;
        }
      }
  }
}

// ---- stage 4: rows qt>=8: out = (out + part)/l ----
__global__ void pv_reduce(float* __restrict__ out, const float* __restrict__ part,
                          const float* __restrict__ l) {
  const int idx = blockIdx.x;           // 4096 = 4b * 1024 rows
  const int b = idx >> 10;
  const int row = 1024 + (idx & 1023);  // global row in [1024, 2048)
  const int t = threadIdx.x;
  const int dt = t >> 5, dl = (t << 2) & 127;
  const float inv = 1.0f / l[((long)b << 11) + row];
  const long pbase = ((((long)b * 8 + ((row >> 7) - 8)) * 8 + dt) << 14) + ((row & 127) << 7) + dl;
  const long obase = (((long)b * 2048 + row) << 10) + (t << 2);
  float4 o = *(const float4*)(out + obase);
  float4 p = *(const float4*)(part + pbase);
  o.x = (o.x + p.x) * inv; o.y = (o.y + p.y) * inv;
  o.z = (o.z + p.z) * inv; o.w = (o.w + p.w) * inv;
  *(float4*)(out + obase) = o;
}

extern "C" void kernel_launch(void* const* d_in, const int* in_sizes, int n_in,
                              void* d_out, int out_size, void* d_ws, size_t ws_size,
                              hipStream_t stream) {
  const float* X  = (const float*)d_in[0];
  const float* Wq = (const float*)d_in[1];
  const float* Wk = (const float*)d_in[2];
  const float* Wv = (const float*)d_in[3];

  char* ws = (char*)d_ws;
  // layout (bytes): Xb 16M (reused as pv partials) | Wt 6M | Q 16M | K 16M | Vt 16M | E 32M | l 32K
  short* Xb = (short*)(ws);
  short* Wt = (short*)(ws + 16777216L);
  short* Q  = (short*)(ws + 23068672L);
  short* K2 = (short*)(ws + 39845888L);
  short* Vt = (short*)(ws + 56623104L);
  short* E  = (short*)(ws + 73400320L);
  float* l  = (float*)(ws + 106954752L);
  float* part = (float*)(ws);  // 256 tiles * 64KB = 16MB, overlays dead Xb

  prep_inputs<<<11296, 256, 0, stream>>>(X, Wq, Wk, Wv, Xb, Wt, l);
  gemm_qkv<<<384, 512, 0, stream>>>(Xb, Wt, Q, K2, Vt);
  scores_exp<<<dim3(72, 4), 256, 0, stream>>>(Q, K2, E, l);
  pv_gemm<<<dim3(96, 4), 256, 0, stream>>>(E, Vt, l, part, (float*)d_out);
  pv_reduce<<<4096, 256, 0, stream>>>((float*)d_out, part, l);
}